// Round 1
// baseline (1530.085 us; speedup 1.0000x reference)
//
#include <hip/hip_runtime.h>
#include <hip/hip_fp16.h>

#define NTOT (1u<<20)   // nodes total
#define ETOT (1u<<24)   // edges total
#define NG   256        // graphs
#define NPG  4096       // nodes per graph
#define EPG  65536      // edges per graph

// ---------------- workspace layout (in 4-byte words) ----------------
constexpr size_t W_OFF  = 0;                       // (NTOT+64) ints: CSR row offsets (global positions)
constexpr size_t W_DEG2 = W_OFF + NTOT + 64;       // NTOT float2: (indeg, outdeg)
constexpr size_t W_SRT  = W_DEG2 + 2*(size_t)NTOT; // ETOT ushorts = ETOT/2 words: sorted local src ids
constexpr size_t W_HA   = W_SRT + ETOT/2;          // NTOT*12 f32
constexpr size_t W_HB   = W_HA + (size_t)NTOT*12;  // NTOT*12 f32
constexpr size_t W_GSUM = W_HB + (size_t)NTOT*12;  // 256*4 f32
constexpr size_t W_SEQ  = W_GSUM + 1024;           // 256*32 f32
constexpr size_t W_PG   = W_SEQ + 8192;            // 256*1024 f32 pregates
constexpr size_t W_W16  = W_PG + 262144;           // 131072 words: W_hh as f16 pairs, transposed [128][1024]

// ---------------- per-graph counting sort (CSR by dst) ----------------
__global__ __launch_bounds__(1024) void k_sort(const int* __restrict__ esrc,
                                               const int* __restrict__ edst,
                                               int* __restrict__ off,
                                               float2* __restrict__ deg2,
                                               unsigned short* __restrict__ srt) {
  __shared__ int hd[NPG];     // indeg hist
  __shared__ int hs[NPG];     // outdeg hist
  __shared__ int cur[NPG];    // scatter cursors (exclusive scan of hd)
  __shared__ int bscan[1024];
  const int g = blockIdx.x;
  const int t = threadIdx.x;
  const int ebase = g * EPG;
  const int nbase = g * NPG;
  for (int i = t; i < NPG; i += 1024) { hd[i] = 0; hs[i] = 0; }
  __syncthreads();
  for (int e = t; e < EPG; e += 1024) {
    int s = esrc[ebase + e] - nbase;
    int d = edst[ebase + e] - nbase;
    atomicAdd(&hs[s], 1);
    atomicAdd(&hd[d], 1);
  }
  __syncthreads();
  // exclusive scan of hd[4096]: 4 per thread + Hillis-Steele over 1024 chunk sums
  int a0 = hd[t*4+0], a1 = hd[t*4+1], a2 = hd[t*4+2], a3 = hd[t*4+3];
  int csum = a0 + a1 + a2 + a3;
  bscan[t] = csum;
  __syncthreads();
  for (int o = 1; o < 1024; o <<= 1) {
    int v = (t >= o) ? bscan[t - o] : 0;
    __syncthreads();
    bscan[t] += v;
    __syncthreads();
  }
  int e0 = bscan[t] - csum;  // exclusive chunk offset
  cur[t*4+0] = e0;
  cur[t*4+1] = e0 + a0;
  cur[t*4+2] = e0 + a0 + a1;
  cur[t*4+3] = e0 + a0 + a1 + a2;
  __syncthreads();
  for (int i = t; i < NPG; i += 1024) {
    off[nbase + i] = ebase + cur[i];
    deg2[nbase + i] = make_float2((float)hd[i], (float)hs[i]);
  }
  if (g == NG - 1 && t == 0) off[NTOT] = (int)ETOT;
  __syncthreads();
  // scatter pass: place src into dst bucket
  for (int e = t; e < EPG; e += 1024) {
    int s = esrc[ebase + e] - nbase;
    int d = edst[ebase + e] - nbase;
    int p = atomicAdd(&cur[d], 1);
    srt[(size_t)ebase + p] = (unsigned short)s;
  }
}

// ---------------- graph conv: aggregate in-edges, then linear+relu ----------------
// grid = 1024 blocks (4 per graph), XCD-swizzled so a graph's blocks share one XCD's L2.
template<int FIN, int FOUT, bool DEGIN, bool POOL>
__global__ __launch_bounds__(256) void k_conv(const int* __restrict__ off,
                                              const unsigned short* __restrict__ srt,
                                              const float* __restrict__ hin,
                                              const float* __restrict__ W,
                                              const float* __restrict__ Bv,
                                              float* __restrict__ hout,
                                              float* __restrict__ gsum) {
  __shared__ float ws[FOUT*FIN + FOUT];
  __shared__ float4 red[256];
  const int b = blockIdx.x;
  const int xcd = b & 7, slot = b >> 3;
  const int g = xcd + 8 * (slot >> 2);   // graph g -> XCD g%8 (assuming round-robin dispatch)
  const int part = slot & 3;
  const int t = threadIdx.x;
  for (int i = t; i < FOUT*FIN + FOUT; i += 256)
    ws[i] = (i < FOUT*FIN) ? W[i] : Bv[i - FOUT*FIN];
  __syncthreads();
  const int nbase = g * NPG;
  float pool[POOL ? FOUT : 1];
  if constexpr (POOL) {
    #pragma unroll
    for (int j = 0; j < FOUT; j++) pool[j] = 0.f;
  }
  #pragma unroll
  for (int k = 0; k < 4; k++) {
    const int n = nbase + part * 1024 + t + k * 256;
    const int e0 = off[n], e1 = off[n + 1];
    float acc[FIN];
    #pragma unroll
    for (int j = 0; j < FIN; j++) acc[j] = 0.f;
    for (int e = e0; e < e1; e++) {
      const int s = nbase + (int)srt[e];
      if constexpr (DEGIN) {
        float2 v = ((const float2*)hin)[s];
        acc[0] += v.x; acc[1] += v.y;
      } else {
        const float4* r = (const float4*)(hin + (size_t)s * 12);
        float4 v0 = r[0], v1 = r[1], v2 = r[2];
        acc[0] += v0.x; acc[1] += v0.y; acc[2]  += v0.z; acc[3]  += v0.w;
        acc[4] += v1.x; acc[5] += v1.y; acc[6]  += v1.z; acc[7]  += v1.w;
        acc[8] += v2.x; acc[9] += v2.y; acc[10] += v2.z; acc[11] += v2.w;
      }
    }
    float o[FOUT];
    #pragma unroll
    for (int j = 0; j < FOUT; j++) {
      float v = ws[FOUT*FIN + j];
      #pragma unroll
      for (int kk = 0; kk < FIN; kk++) v += ws[j*FIN + kk] * acc[kk];
      o[j] = fmaxf(v, 0.f);
    }
    if constexpr (!POOL) {
      float4* wout = (float4*)(hout + (size_t)n * 12);
      wout[0] = make_float4(o[0], o[1], o[2],  o[3]);
      wout[1] = make_float4(o[4], o[5], o[6],  o[7]);
      wout[2] = make_float4(o[8], o[9], o[10], o[11]);
    } else {
      #pragma unroll
      for (int j = 0; j < FOUT; j++) pool[j] += o[j];
    }
  }
  if constexpr (POOL) {
    red[t] = make_float4(pool[0], pool[1], pool[2], pool[3]);
    __syncthreads();
    for (int o2 = 128; o2 > 0; o2 >>= 1) {
      if (t < o2) {
        red[t].x += red[t + o2].x; red[t].y += red[t + o2].y;
        red[t].z += red[t + o2].z; red[t].w += red[t + o2].w;
      }
      __syncthreads();
    }
    if (t == 0) {
      atomicAdd(&gsum[g*4+0], red[0].x);
      atomicAdd(&gsum[g*4+1], red[0].y);
      atomicAdd(&gsum[g*4+2], red[0].z);
      atomicAdd(&gsum[g*4+3], red[0].w);
    }
  }
}

// ---------------- fc1 + concat -> seq [256][32] ----------------
__global__ __launch_bounds__(256) void k_small(const float* __restrict__ x,
                                               const float* __restrict__ fw,
                                               const float* __restrict__ fb,
                                               const float* __restrict__ gsum,
                                               float* __restrict__ seq) {
  const int t = threadIdx.x;  // graph / seq row
  float xv[64];
  #pragma unroll
  for (int k = 0; k < 64; k++) xv[k] = x[t*64 + k];
  for (int j = 0; j < 28; j++) {
    float acc = fb[j];
    #pragma unroll
    for (int k = 0; k < 64; k++) acc += fw[j*64 + k] * xv[k];
    seq[t*32 + j] = fmaxf(acc, 0.f);
  }
  #pragma unroll
  for (int f = 0; f < 4; f++)
    seq[t*32 + 28 + f] = gsum[t*4 + f] * (1.0f / 4096.0f);
}

// ---------------- input-side gates: pg[step][row] = b_ih+b_hh + W_ih@xt ----------------
__global__ __launch_bounds__(256) void k_pregates(const float* __restrict__ Wih,
                                                  const float* __restrict__ bih,
                                                  const float* __restrict__ bhh,
                                                  const float* __restrict__ seq,
                                                  float* __restrict__ pg) {
  const int b = blockIdx.x;
  const int step = b >> 2;
  const int row = (b & 3) * 256 + threadIdx.x;
  const float* sr = seq + step * 32;
  float acc = bih[row] + bhh[row];
  const float4* wr = (const float4*)(Wih + (size_t)row * 32);
  #pragma unroll
  for (int c = 0; c < 8; c++) {
    float4 w = wr[c];
    acc += w.x * sr[4*c+0] + w.y * sr[4*c+1] + w.z * sr[4*c+2] + w.w * sr[4*c+3];
  }
  pg[(size_t)step * 1024 + row] = acc;
}

// ---------------- W_hh f32 -> f16 pairs, transposed [pair j][row t] ----------------
__global__ __launch_bounds__(256) void k_w16(const float* __restrict__ Whh,
                                             unsigned int* __restrict__ w16) {
  const int p = blockIdx.x * 256 + threadIdx.x;   // 131072
  const int t = p >> 7, j = p & 127;
  float2 v = ((const float2*)Whh)[(size_t)t * 128 + j];
  __half2 h = __floats2half2_rn(v.x, v.y);
  w16[(size_t)j * 1024 + t] = *(unsigned int*)&h;
}

// ---------------- LSTM: single workgroup, W_hh f16 resident in VGPR+LDS ----------------
typedef _Float16 half2_t __attribute__((ext_vector_type(2)));

__device__ inline float dot2(unsigned int a, unsigned int b, float c) {
#if defined(__has_builtin) && __has_builtin(__builtin_amdgcn_fdot2)
  return __builtin_amdgcn_fdot2(__builtin_bit_cast(half2_t, a),
                                __builtin_bit_cast(half2_t, b), c, false);
#else
  __half2 ha = *(__half2*)&a, hb = *(__half2*)&b;
  float2 fa = __half22float2(ha), fb = __half22float2(hb);
  return c + fa.x * fb.x + fa.y * fb.y;
#endif
}

#define LSTM_LDS_BYTES (9*1024*16 + 4096 + 512)

__global__ __launch_bounds__(1024, 1) void k_lstm(const unsigned int* __restrict__ w16,
                                                  const float* __restrict__ pg,
                                                  float* __restrict__ out) {
  extern __shared__ char smem[];
  uint4* wlds = (uint4*)smem;                                  // [9][1024] b128 per thread
  float* gates = (float*)(smem + 9*1024*16);                   // 1024 f32
  unsigned int* hbuf = (unsigned int*)(smem + 9*1024*16 + 4096); // 128 uints = 256 f16
  const int t = threadIdx.x;  // gate row
  unsigned int wr[92];
  #pragma unroll
  for (int j = 0; j < 92; j++) wr[j] = w16[(size_t)j * 1024 + t];
  #pragma unroll
  for (int c = 0; c < 9; c++) {
    wlds[c*1024 + t] = make_uint4(w16[(size_t)(92 + 4*c + 0) * 1024 + t],
                                  w16[(size_t)(92 + 4*c + 1) * 1024 + t],
                                  w16[(size_t)(92 + 4*c + 2) * 1024 + t],
                                  w16[(size_t)(92 + 4*c + 3) * 1024 + t]);
  }
  if (t < 128) hbuf[t] = 0u;   // h0 = 0
  float c_state = 0.f;
  __syncthreads();
  const uint4* h4 = (const uint4*)hbuf;
  for (int step = 0; step < 256; ++step) {
    float acc = pg[(size_t)step * 1024 + t];
    #pragma unroll
    for (int c = 0; c < 23; c++) {          // register-resident 92 pairs
      uint4 hh = h4[c];
      acc = dot2(wr[4*c+0], hh.x, acc);
      acc = dot2(wr[4*c+1], hh.y, acc);
      acc = dot2(wr[4*c+2], hh.z, acc);
      acc = dot2(wr[4*c+3], hh.w, acc);
    }
    #pragma unroll
    for (int c = 0; c < 9; c++) {           // LDS-resident 36 pairs
      uint4 ww = wlds[c*1024 + t];
      uint4 hh = h4[23 + c];
      acc = dot2(ww.x, hh.x, acc);
      acc = dot2(ww.y, hh.y, acc);
      acc = dot2(ww.z, hh.z, acc);
      acc = dot2(ww.w, hh.w, acc);
    }
    gates[t] = acc;
    __syncthreads();
    if (t < 256) {
      float gi = gates[t], gf = gates[t+256], gg = gates[t+512], go = gates[t+768];
      float si = 1.f / (1.f + __expf(-gi));
      float sf = 1.f / (1.f + __expf(-gf));
      float so = 1.f / (1.f + __expf(-go));
      float tg = tanhf(gg);
      c_state = sf * c_state + si * tg;
      float hn = so * tanhf(c_state);
      out[step*256 + t] = hn;
      ((unsigned short*)hbuf)[t] = __half_as_ushort(__float2half(hn));
    }
    __syncthreads();
  }
}

extern "C" void kernel_launch(void* const* d_in, const int* in_sizes, int n_in,
                              void* d_out, int out_size, void* d_ws, size_t ws_size,
                              hipStream_t stream) {
  const float* x    = (const float*)d_in[0];
  const int*   esrc = (const int*)d_in[1];
  const int*   edst = (const int*)d_in[2];
  // d_in[3] node_graph_ids: implied by node index (n >> 12)
  const float* fc1w = (const float*)d_in[4];
  const float* fc1b = (const float*)d_in[5];
  const float* g1w  = (const float*)d_in[6];
  const float* g1b  = (const float*)d_in[7];
  const float* g2w  = (const float*)d_in[8];
  const float* g2b  = (const float*)d_in[9];
  const float* g3w  = (const float*)d_in[10];
  const float* g3b  = (const float*)d_in[11];
  const float* Wih  = (const float*)d_in[12];
  const float* Whh  = (const float*)d_in[13];
  const float* bih  = (const float*)d_in[14];
  const float* bhh  = (const float*)d_in[15];
  // d_in[16], d_in[17]: w_omega/u_omega — result discarded by reference

  float* ws = (float*)d_ws;
  int*            off  = (int*)(ws + W_OFF);
  float*          deg2 = ws + W_DEG2;
  unsigned short* srt  = (unsigned short*)(ws + W_SRT);
  float*          ha   = ws + W_HA;
  float*          hb   = ws + W_HB;
  float*          gsum = ws + W_GSUM;
  float*          seq  = ws + W_SEQ;
  float*          pg   = ws + W_PG;
  unsigned int*   w16  = (unsigned int*)(ws + W_W16);

  hipMemsetAsync(gsum, 0, 1024 * 4, stream);
  k_sort<<<256, 1024, 0, stream>>>(esrc, edst, off, (float2*)deg2, srt);
  k_conv<2, 12, true,  false><<<1024, 256, 0, stream>>>(off, srt, deg2, g1w, g1b, ha, nullptr);
  k_conv<12, 12, false, false><<<1024, 256, 0, stream>>>(off, srt, ha, g2w, g2b, hb, nullptr);
  k_conv<12, 4, false, true ><<<1024, 256, 0, stream>>>(off, srt, hb, g3w, g3b, nullptr, gsum);
  k_small<<<1, 256, 0, stream>>>(x, fc1w, fc1b, gsum, seq);
  k_pregates<<<1024, 256, 0, stream>>>(Wih, bih, bhh, seq, pg);
  k_w16<<<512, 256, 0, stream>>>(Whh, w16);
  k_lstm<<<1, 1024, LSTM_LDS_BYTES, stream>>>(w16, pg, (float*)d_out);
}

// Round 2
// 1431.364 us; speedup vs baseline: 1.0690x; 1.0690x over previous
//
#include <hip/hip_runtime.h>
#include <hip/hip_fp16.h>

#define NTOT (1u<<20)   // nodes total
#define ETOT (1u<<24)   // edges total
#define NG   256        // graphs
#define NPG  4096       // nodes per graph
#define EPG  65536      // edges per graph

// ---------------- workspace layout (in 4-byte words) ----------------
constexpr size_t W_OFF  = 0;                       // (NTOT+64) ints: CSR row offsets (global positions)
constexpr size_t W_DEG2 = W_OFF + NTOT + 64;       // NTOT float2: (indeg, outdeg)
constexpr size_t W_SRT  = W_DEG2 + 2*(size_t)NTOT; // ETOT ushorts = ETOT/2 words: sorted local src ids
constexpr size_t W_HA   = W_SRT + ETOT/2;          // NTOT*12 f32
constexpr size_t W_HB   = W_HA + (size_t)NTOT*12;  // NTOT*12 f32
constexpr size_t W_GSUM = W_HB + (size_t)NTOT*12;  // 256*4 f32
constexpr size_t W_SEQ  = W_GSUM + 1024;           // 256*32 f32
constexpr size_t W_PG   = W_SEQ + 8192;            // 256*1024 f32 pregates
constexpr size_t W_W16  = W_PG + 262144;           // 131072 words: W_hh as f16 pairs, transposed [128][1024]

// ---------------- per-graph counting sort (CSR by dst) ----------------
__global__ __launch_bounds__(1024) void k_sort(const int* __restrict__ esrc,
                                               const int* __restrict__ edst,
                                               int* __restrict__ off,
                                               float2* __restrict__ deg2,
                                               unsigned short* __restrict__ srt) {
  __shared__ int hd[NPG];     // indeg hist
  __shared__ int hs[NPG];     // outdeg hist
  __shared__ int cur[NPG];    // scatter cursors (exclusive scan of hd)
  __shared__ int bscan[1024];
  const int g = blockIdx.x;
  const int t = threadIdx.x;
  const int ebase = g * EPG;
  const int nbase = g * NPG;
  for (int i = t; i < NPG; i += 1024) { hd[i] = 0; hs[i] = 0; }
  __syncthreads();
  for (int e = t; e < EPG; e += 1024) {
    int s = esrc[ebase + e] - nbase;
    int d = edst[ebase + e] - nbase;
    atomicAdd(&hs[s], 1);
    atomicAdd(&hd[d], 1);
  }
  __syncthreads();
  // exclusive scan of hd[4096]: 4 per thread + Hillis-Steele over 1024 chunk sums
  int a0 = hd[t*4+0], a1 = hd[t*4+1], a2 = hd[t*4+2], a3 = hd[t*4+3];
  int csum = a0 + a1 + a2 + a3;
  bscan[t] = csum;
  __syncthreads();
  for (int o = 1; o < 1024; o <<= 1) {
    int v = (t >= o) ? bscan[t - o] : 0;
    __syncthreads();
    bscan[t] += v;
    __syncthreads();
  }
  int e0 = bscan[t] - csum;  // exclusive chunk offset
  cur[t*4+0] = e0;
  cur[t*4+1] = e0 + a0;
  cur[t*4+2] = e0 + a0 + a1;
  cur[t*4+3] = e0 + a0 + a1 + a2;
  __syncthreads();
  for (int i = t; i < NPG; i += 1024) {
    off[nbase + i] = ebase + cur[i];
    deg2[nbase + i] = make_float2((float)hd[i], (float)hs[i]);
  }
  if (g == NG - 1 && t == 0) off[NTOT] = (int)ETOT;
  __syncthreads();
  // scatter pass: place src into dst bucket
  for (int e = t; e < EPG; e += 1024) {
    int s = esrc[ebase + e] - nbase;
    int d = edst[ebase + e] - nbase;
    int p = atomicAdd(&cur[d], 1);
    srt[(size_t)ebase + p] = (unsigned short)s;
  }
}

// ---------------- graph conv: aggregate in-edges, then linear+relu ----------------
// grid = 1024 blocks (4 per graph), XCD-swizzled so a graph's blocks share one XCD's L2.
template<int FIN, int FOUT, bool DEGIN, bool POOL>
__global__ __launch_bounds__(256) void k_conv(const int* __restrict__ off,
                                              const unsigned short* __restrict__ srt,
                                              const float* __restrict__ hin,
                                              const float* __restrict__ W,
                                              const float* __restrict__ Bv,
                                              float* __restrict__ hout,
                                              float* __restrict__ gsum) {
  __shared__ float ws[FOUT*FIN + FOUT];
  __shared__ float4 red[256];
  const int b = blockIdx.x;
  const int xcd = b & 7, slot = b >> 3;
  const int g = xcd + 8 * (slot >> 2);   // graph g -> XCD g%8 (assuming round-robin dispatch)
  const int part = slot & 3;
  const int t = threadIdx.x;
  for (int i = t; i < FOUT*FIN + FOUT; i += 256)
    ws[i] = (i < FOUT*FIN) ? W[i] : Bv[i - FOUT*FIN];
  __syncthreads();
  const int nbase = g * NPG;
  float pool[POOL ? FOUT : 1];
  if constexpr (POOL) {
    #pragma unroll
    for (int j = 0; j < FOUT; j++) pool[j] = 0.f;
  }
  #pragma unroll
  for (int k = 0; k < 4; k++) {
    const int n = nbase + part * 1024 + t + k * 256;
    const int e0 = off[n], e1 = off[n + 1];
    float acc[FIN];
    #pragma unroll
    for (int j = 0; j < FIN; j++) acc[j] = 0.f;
    for (int e = e0; e < e1; e++) {
      const int s = nbase + (int)srt[e];
      if constexpr (DEGIN) {
        float2 v = ((const float2*)hin)[s];
        acc[0] += v.x; acc[1] += v.y;
      } else {
        const float4* r = (const float4*)(hin + (size_t)s * 12);
        float4 v0 = r[0], v1 = r[1], v2 = r[2];
        acc[0] += v0.x; acc[1] += v0.y; acc[2]  += v0.z; acc[3]  += v0.w;
        acc[4] += v1.x; acc[5] += v1.y; acc[6]  += v1.z; acc[7]  += v1.w;
        acc[8] += v2.x; acc[9] += v2.y; acc[10] += v2.z; acc[11] += v2.w;
      }
    }
    float o[FOUT];
    #pragma unroll
    for (int j = 0; j < FOUT; j++) {
      float v = ws[FOUT*FIN + j];
      #pragma unroll
      for (int kk = 0; kk < FIN; kk++) v += ws[j*FIN + kk] * acc[kk];
      o[j] = fmaxf(v, 0.f);
    }
    if constexpr (!POOL) {
      float4* wout = (float4*)(hout + (size_t)n * 12);
      wout[0] = make_float4(o[0], o[1], o[2],  o[3]);
      wout[1] = make_float4(o[4], o[5], o[6],  o[7]);
      wout[2] = make_float4(o[8], o[9], o[10], o[11]);
    } else {
      #pragma unroll
      for (int j = 0; j < FOUT; j++) pool[j] += o[j];
    }
  }
  if constexpr (POOL) {
    red[t] = make_float4(pool[0], pool[1], pool[2], pool[3]);
    __syncthreads();
    for (int o2 = 128; o2 > 0; o2 >>= 1) {
      if (t < o2) {
        red[t].x += red[t + o2].x; red[t].y += red[t + o2].y;
        red[t].z += red[t + o2].z; red[t].w += red[t + o2].w;
      }
      __syncthreads();
    }
    if (t == 0) {
      atomicAdd(&gsum[g*4+0], red[0].x);
      atomicAdd(&gsum[g*4+1], red[0].y);
      atomicAdd(&gsum[g*4+2], red[0].z);
      atomicAdd(&gsum[g*4+3], red[0].w);
    }
  }
}

// ---------------- fc1 + concat -> seq [256][32] ----------------
__global__ __launch_bounds__(256) void k_small(const float* __restrict__ x,
                                               const float* __restrict__ fw,
                                               const float* __restrict__ fb,
                                               const float* __restrict__ gsum,
                                               float* __restrict__ seq) {
  const int t = threadIdx.x;  // graph / seq row
  float xv[64];
  #pragma unroll
  for (int k = 0; k < 64; k++) xv[k] = x[t*64 + k];
  for (int j = 0; j < 28; j++) {
    float acc = fb[j];
    #pragma unroll
    for (int k = 0; k < 64; k++) acc += fw[j*64 + k] * xv[k];
    seq[t*32 + j] = fmaxf(acc, 0.f);
  }
  #pragma unroll
  for (int f = 0; f < 4; f++)
    seq[t*32 + 28 + f] = gsum[t*4 + f] * (1.0f / 4096.0f);
}

// ---------------- input-side gates: pg[step][row] = b_ih+b_hh + W_ih@xt ----------------
__global__ __launch_bounds__(256) void k_pregates(const float* __restrict__ Wih,
                                                  const float* __restrict__ bih,
                                                  const float* __restrict__ bhh,
                                                  const float* __restrict__ seq,
                                                  float* __restrict__ pg) {
  const int b = blockIdx.x;
  const int step = b >> 2;
  const int row = (b & 3) * 256 + threadIdx.x;
  const float* sr = seq + step * 32;
  float acc = bih[row] + bhh[row];
  const float4* wr = (const float4*)(Wih + (size_t)row * 32);
  #pragma unroll
  for (int c = 0; c < 8; c++) {
    float4 w = wr[c];
    acc += w.x * sr[4*c+0] + w.y * sr[4*c+1] + w.z * sr[4*c+2] + w.w * sr[4*c+3];
  }
  pg[(size_t)step * 1024 + row] = acc;
}

// ---------------- W_hh f32 -> f16 pairs, transposed [pair j][row t] ----------------
__global__ __launch_bounds__(256) void k_w16(const float* __restrict__ Whh,
                                             unsigned int* __restrict__ w16) {
  const int p = blockIdx.x * 256 + threadIdx.x;   // 131072
  const int t = p >> 7, j = p & 127;
  float2 v = ((const float2*)Whh)[(size_t)t * 128 + j];
  __half2 h = __floats2half2_rn(v.x, v.y);
  w16[(size_t)j * 1024 + t] = *(unsigned int*)&h;
}

// ---------------- LSTM: single workgroup, 512 thr x 2 rows, W_hh f16 in VGPR+LDS ----------------
typedef _Float16 half2_t __attribute__((ext_vector_type(2)));

__device__ inline float dot2(unsigned int a, unsigned int b, float c) {
#if defined(__has_builtin) && __has_builtin(__builtin_amdgcn_fdot2)
  return __builtin_amdgcn_fdot2(__builtin_bit_cast(half2_t, a),
                                __builtin_bit_cast(half2_t, b), c, false);
#else
  __half2 ha = *(__half2*)&a, hb = *(__half2*)&b;
  float2 fa = __half22float2(ha), fb = __half22float2(hb);
  return c + fa.x * fb.x + fa.y * fb.y;
#endif
}

// P_REG = 104 pairs/row in VGPR (2 rows -> 208 regs), P_LDS = 24 pairs/row in LDS.
// LDS weight layout: [512 thr][2 rows][8 uint4 slots] with slot = c ^ (t&7) XOR swizzle
// (8 slots x 16B = 128B spans all 32 banks; without swizzle all lanes hit one 4-bank group).
#define LSTM_WLDS_BYTES (512*2*8*16)              // 131072
#define LSTM_GEX_OFF    LSTM_WLDS_BYTES
#define LSTM_HBUF_OFF   (LSTM_WLDS_BYTES + 4096)
#define LSTM_LDS_BYTES  (LSTM_WLDS_BYTES + 4096 + 512)

__device__ inline float fast_sig(float x) {
  return 1.f / (1.f + __expf(-x));
}
__device__ inline float fast_tanh(float x) {
  float xc = fminf(fmaxf(x, -30.f), 30.f);   // avoid inf/inf
  float e = __expf(2.f * xc);
  return (e - 1.f) / (e + 1.f);
}

__global__ __attribute__((amdgpu_waves_per_eu(2, 2))) __launch_bounds__(512)
void k_lstm(const unsigned int* __restrict__ w16,
            const float* __restrict__ pg,
            float* __restrict__ out) {
  extern __shared__ char smem[];
  uint4* wlds = (uint4*)smem;
  float* gex = (float*)(smem + LSTM_GEX_OFF);                 // 1024 f32
  unsigned int* hbuf = (unsigned int*)(smem + LSTM_HBUF_OFF); // 128 uints = 256 f16
  const int t = threadIdx.x;          // owns rows t and t+512
  const int swz = t & 7;
  unsigned int wrA[104], wrB[104];
  #pragma unroll
  for (int j = 0; j < 104; j++) {
    wrA[j] = w16[(size_t)j * 1024 + t];
    wrB[j] = w16[(size_t)j * 1024 + t + 512];
  }
  #pragma unroll
  for (int c = 0; c < 6; c++) {
    uint4 a, b;
    a.x = w16[(size_t)(104 + 4*c + 0) * 1024 + t];
    a.y = w16[(size_t)(104 + 4*c + 1) * 1024 + t];
    a.z = w16[(size_t)(104 + 4*c + 2) * 1024 + t];
    a.w = w16[(size_t)(104 + 4*c + 3) * 1024 + t];
    b.x = w16[(size_t)(104 + 4*c + 0) * 1024 + t + 512];
    b.y = w16[(size_t)(104 + 4*c + 1) * 1024 + t + 512];
    b.z = w16[(size_t)(104 + 4*c + 2) * 1024 + t + 512];
    b.w = w16[(size_t)(104 + 4*c + 3) * 1024 + t + 512];
    wlds[(t*2 + 0) * 8 + (c ^ swz)] = a;
    wlds[(t*2 + 1) * 8 + (c ^ swz)] = b;
  }
  if (t < 128) hbuf[t] = 0u;   // h0 = 0
  float cs = 0.f;              // c_state, live in threads t<256
  __syncthreads();
  const uint4* h4 = (const uint4*)hbuf;
  float p0 = pg[t], p1 = pg[t + 512];   // software-pipelined pregate loads
  for (int step = 0; step < 256; ++step) {
    float n0 = 0.f, n1 = 0.f;
    if (step < 255) {
      n0 = pg[(size_t)(step + 1) * 1024 + t];
      n1 = pg[(size_t)(step + 1) * 1024 + t + 512];
    }
    float a0 = p0, a1 = p1;
    #pragma unroll
    for (int c = 0; c < 26; c++) {       // register-resident 104 pairs/row
      uint4 hh = h4[c];
      a0 = dot2(wrA[4*c+0], hh.x, a0);
      a0 = dot2(wrA[4*c+1], hh.y, a0);
      a0 = dot2(wrA[4*c+2], hh.z, a0);
      a0 = dot2(wrA[4*c+3], hh.w, a0);
      a1 = dot2(wrB[4*c+0], hh.x, a1);
      a1 = dot2(wrB[4*c+1], hh.y, a1);
      a1 = dot2(wrB[4*c+2], hh.z, a1);
      a1 = dot2(wrB[4*c+3], hh.w, a1);
    }
    #pragma unroll
    for (int c = 0; c < 6; c++) {        // LDS-resident 24 pairs/row
      uint4 hh = h4[26 + c];
      uint4 wa = wlds[(t*2 + 0) * 8 + (c ^ swz)];
      uint4 wb = wlds[(t*2 + 1) * 8 + (c ^ swz)];
      a0 = dot2(wa.x, hh.x, a0);
      a0 = dot2(wa.y, hh.y, a0);
      a0 = dot2(wa.z, hh.z, a0);
      a0 = dot2(wa.w, hh.w, a0);
      a1 = dot2(wb.x, hh.x, a1);
      a1 = dot2(wb.y, hh.y, a1);
      a1 = dot2(wb.z, hh.z, a1);
      a1 = dot2(wb.w, hh.w, a1);
    }
    gex[t] = a0;
    gex[t + 512] = a1;
    __syncthreads();
    if (t < 256) {
      float gi = gex[t], gf = gex[t + 256], gg = gex[t + 512], go = gex[t + 768];
      float si = fast_sig(gi);
      float sf = fast_sig(gf);
      float so = fast_sig(go);
      float tg = fast_tanh(gg);
      cs = sf * cs + si * tg;
      float hn = so * fast_tanh(cs);
      out[step * 256 + t] = hn;
      ((unsigned short*)hbuf)[t] = __half_as_ushort(__float2half(hn));
    }
    __syncthreads();
    p0 = n0;
    p1 = n1;
  }
}

extern "C" void kernel_launch(void* const* d_in, const int* in_sizes, int n_in,
                              void* d_out, int out_size, void* d_ws, size_t ws_size,
                              hipStream_t stream) {
  const float* x    = (const float*)d_in[0];
  const int*   esrc = (const int*)d_in[1];
  const int*   edst = (const int*)d_in[2];
  // d_in[3] node_graph_ids: implied by node index (n >> 12)
  const float* fc1w = (const float*)d_in[4];
  const float* fc1b = (const float*)d_in[5];
  const float* g1w  = (const float*)d_in[6];
  const float* g1b  = (const float*)d_in[7];
  const float* g2w  = (const float*)d_in[8];
  const float* g2b  = (const float*)d_in[9];
  const float* g3w  = (const float*)d_in[10];
  const float* g3b  = (const float*)d_in[11];
  const float* Wih  = (const float*)d_in[12];
  const float* Whh  = (const float*)d_in[13];
  const float* bih  = (const float*)d_in[14];
  const float* bhh  = (const float*)d_in[15];
  // d_in[16], d_in[17]: w_omega/u_omega — result discarded by reference

  float* ws = (float*)d_ws;
  int*            off  = (int*)(ws + W_OFF);
  float*          deg2 = ws + W_DEG2;
  unsigned short* srt  = (unsigned short*)(ws + W_SRT);
  float*          ha   = ws + W_HA;
  float*          hb   = ws + W_HB;
  float*          gsum = ws + W_GSUM;
  float*          seq  = ws + W_SEQ;
  float*          pg   = ws + W_PG;
  unsigned int*   w16  = (unsigned int*)(ws + W_W16);

  hipMemsetAsync(gsum, 0, 1024 * 4, stream);
  k_w16<<<512, 256, 0, stream>>>(Whh, w16);
  k_sort<<<256, 1024, 0, stream>>>(esrc, edst, off, (float2*)deg2, srt);
  k_conv<2, 12, true,  false><<<1024, 256, 0, stream>>>(off, srt, deg2, g1w, g1b, ha, nullptr);
  k_conv<12, 12, false, false><<<1024, 256, 0, stream>>>(off, srt, ha, g2w, g2b, hb, nullptr);
  k_conv<12, 4, false, true ><<<1024, 256, 0, stream>>>(off, srt, hb, g3w, g3b, nullptr, gsum);
  k_small<<<1, 256, 0, stream>>>(x, fc1w, fc1b, gsum, seq);
  k_pregates<<<1024, 256, 0, stream>>>(Wih, bih, bhh, seq, pg);
  k_lstm<<<1, 512, LSTM_LDS_BYTES, stream>>>(w16, pg, (float*)d_out);
}

// Round 3
// 932.393 us; speedup vs baseline: 1.6410x; 1.5352x over previous
//
#include <hip/hip_runtime.h>
#include <hip/hip_fp16.h>

#define NTOT (1u<<20)   // nodes total
#define ETOT (1u<<24)   // edges total
#define NG   256        // graphs
#define NPG  4096       // nodes per graph
#define EPG  65536      // edges per graph

// ---------------- workspace layout (in 4-byte words) ----------------
constexpr size_t W_OFF  = 0;                       // (NTOT+64) ints: CSR row offsets (global positions)
constexpr size_t W_DEG2 = W_OFF + NTOT + 64;       // NTOT float2: (indeg, outdeg)
constexpr size_t W_SRT  = W_DEG2 + 2*(size_t)NTOT; // ETOT ushorts = ETOT/2 words: sorted local src ids
constexpr size_t W_HA   = W_SRT + ETOT/2;          // NTOT*12 f32
constexpr size_t W_HB   = W_HA + (size_t)NTOT*12;  // NTOT*12 f32
constexpr size_t W_GSUM = W_HB + (size_t)NTOT*12;  // 256*4 f32
constexpr size_t W_SEQ  = W_GSUM + 1024;           // 256*32 f32
constexpr size_t W_PG   = W_SEQ + 8192;            // 256*1024 f32 pregates
constexpr size_t W_W16  = W_PG + 262144;           // 131072 words: W_hh as f16 pairs, transposed [128][1024]

// ---------------- per-graph counting sort (CSR by dst), scatter staged in LDS ----------------
// LDS: [0,16K) cur | [16K,20K) bscan | [20K,148K) region C = hd[16K]+hs[16K], reused as slds[128K]
#define SORT_LDS_BYTES (16384 + 4096 + 131072)
__global__ __launch_bounds__(1024) void k_sort(const int* __restrict__ esrc,
                                               const int* __restrict__ edst,
                                               int* __restrict__ off,
                                               float2* __restrict__ deg2,
                                               unsigned short* __restrict__ srt) {
  extern __shared__ char sm[];
  int* cur   = (int*)sm;                   // [4096]
  int* bscan = (int*)(sm + 16384);         // [1024]
  int* hd    = (int*)(sm + 20480);         // [4096]
  int* hs    = (int*)(sm + 20480 + 16384); // [4096]
  unsigned short* slds = (unsigned short*)(sm + 20480);  // [65536], reuses hd/hs space
  const int g = blockIdx.x;
  const int t = threadIdx.x;
  const int ebase = g * EPG;
  const int nbase = g * NPG;
  for (int i = t; i < NPG; i += 1024) { hd[i] = 0; hs[i] = 0; }
  __syncthreads();
  for (int e = t; e < EPG; e += 1024) {
    int s = esrc[ebase + e] - nbase;
    int d = edst[ebase + e] - nbase;
    atomicAdd(&hs[s], 1);
    atomicAdd(&hd[d], 1);
  }
  __syncthreads();
  // exclusive scan of hd[4096]: 4 per thread + Hillis-Steele over 1024 chunk sums
  int a0 = hd[t*4+0], a1 = hd[t*4+1], a2 = hd[t*4+2], a3 = hd[t*4+3];
  int csum = a0 + a1 + a2 + a3;
  bscan[t] = csum;
  __syncthreads();
  for (int o = 1; o < 1024; o <<= 1) {
    int v = (t >= o) ? bscan[t - o] : 0;
    __syncthreads();
    bscan[t] += v;
    __syncthreads();
  }
  int e0 = bscan[t] - csum;  // exclusive chunk offset
  cur[t*4+0] = e0;
  cur[t*4+1] = e0 + a0;
  cur[t*4+2] = e0 + a0 + a1;
  cur[t*4+3] = e0 + a0 + a1 + a2;
  __syncthreads();
  for (int i = t; i < NPG; i += 1024) {
    off[nbase + i] = ebase + cur[i];
    deg2[nbase + i] = make_float2((float)hd[i], (float)hs[i]);
  }
  if (g == NG - 1 && t == 0) off[NTOT] = (int)ETOT;
  __syncthreads();   // hd/hs fully consumed; region C becomes slds
  // scatter pass into LDS: place src into dst bucket
  for (int e = t; e < EPG; e += 1024) {
    int s = esrc[ebase + e] - nbase;
    int d = edst[ebase + e] - nbase;
    int p = atomicAdd(&cur[d], 1);
    slds[p] = (unsigned short)s;
  }
  __syncthreads();
  // coalesced stream-out: 128KB as 8192 x uint4
  uint4* dstv = (uint4*)(srt + (size_t)ebase);
  const uint4* srcv = (const uint4*)slds;
  for (int i = t; i < 8192; i += 1024)
    dstv[i] = srcv[i];
}

// ---------------- graph conv: aggregate in-edges, then linear+relu ----------------
// grid = 4096 blocks (16 per graph, 1 node/thread), XCD-swizzled: all blocks of a
// graph share blockIdx%8 -> same XCD L2 (round-robin dispatch heuristic).
template<int FIN, int FOUT, bool DEGIN, bool POOL>
__global__ __launch_bounds__(256) void k_conv(const int* __restrict__ off,
                                              const unsigned short* __restrict__ srt,
                                              const float* __restrict__ hin,
                                              const float* __restrict__ W,
                                              const float* __restrict__ Bv,
                                              float* __restrict__ hout,
                                              float* __restrict__ gsum) {
  __shared__ float wsm[FOUT*FIN + FOUT];
  __shared__ float4 red[POOL ? 256 : 1];
  const int b = blockIdx.x;
  const int t = threadIdx.x;
  const int xcd = b & 7, slot = b >> 3;
  const int part = slot & 15, gidx = slot >> 4;   // 16 parts/graph, 32 graphs/XCD
  const int g = xcd + 8 * gidx;
  for (int i = t; i < FOUT*FIN + FOUT; i += 256)
    wsm[i] = (i < FOUT*FIN) ? W[i] : Bv[i - FOUT*FIN];
  __syncthreads();
  const int nbase = g * NPG;
  const int n = nbase + part * 256 + t;
  const int e0 = off[n], e1 = off[n + 1];
  float acc[FIN];
  #pragma unroll
  for (int j = 0; j < FIN; j++) acc[j] = 0.f;
  #pragma unroll 4
  for (int e = e0; e < e1; e++) {
    const int s = nbase + (int)srt[e];
    if constexpr (DEGIN) {
      float2 v = ((const float2*)hin)[s];
      acc[0] += v.x; acc[1] += v.y;
    } else {
      const float4* r = (const float4*)(hin + (size_t)s * 12);
      float4 v0 = r[0], v1 = r[1], v2 = r[2];
      acc[0] += v0.x; acc[1] += v0.y; acc[2]  += v0.z; acc[3]  += v0.w;
      acc[4] += v1.x; acc[5] += v1.y; acc[6]  += v1.z; acc[7]  += v1.w;
      acc[8] += v2.x; acc[9] += v2.y; acc[10] += v2.z; acc[11] += v2.w;
    }
  }
  float o[FOUT];
  #pragma unroll
  for (int j = 0; j < FOUT; j++) {
    float v = wsm[FOUT*FIN + j];
    #pragma unroll
    for (int kk = 0; kk < FIN; kk++) v += wsm[j*FIN + kk] * acc[kk];
    o[j] = fmaxf(v, 0.f);
  }
  if constexpr (!POOL) {
    float4* wout = (float4*)(hout + (size_t)n * 12);
    wout[0] = make_float4(o[0], o[1], o[2],  o[3]);
    wout[1] = make_float4(o[4], o[5], o[6],  o[7]);
    wout[2] = make_float4(o[8], o[9], o[10], o[11]);
  } else {
    red[t] = make_float4(o[0], o[1], o[2], o[3]);
    __syncthreads();
    for (int o2 = 128; o2 > 0; o2 >>= 1) {
      if (t < o2) {
        red[t].x += red[t + o2].x; red[t].y += red[t + o2].y;
        red[t].z += red[t + o2].z; red[t].w += red[t + o2].w;
      }
      __syncthreads();
    }
    if (t == 0) {
      atomicAdd(&gsum[g*4+0], red[0].x);
      atomicAdd(&gsum[g*4+1], red[0].y);
      atomicAdd(&gsum[g*4+2], red[0].z);
      atomicAdd(&gsum[g*4+3], red[0].w);
    }
  }
}

// ---------------- fc1 + concat -> seq [256][32] ----------------
__global__ __launch_bounds__(256) void k_small(const float* __restrict__ x,
                                               const float* __restrict__ fw,
                                               const float* __restrict__ fb,
                                               const float* __restrict__ gsum,
                                               float* __restrict__ seq) {
  const int t = threadIdx.x;  // graph / seq row
  float xv[64];
  #pragma unroll
  for (int k = 0; k < 64; k++) xv[k] = x[t*64 + k];
  for (int j = 0; j < 28; j++) {
    float acc = fb[j];
    #pragma unroll
    for (int k = 0; k < 64; k++) acc += fw[j*64 + k] * xv[k];
    seq[t*32 + j] = fmaxf(acc, 0.f);
  }
  #pragma unroll
  for (int f = 0; f < 4; f++)
    seq[t*32 + 28 + f] = gsum[t*4 + f] * (1.0f / 4096.0f);
}

// ---------------- input-side gates: pg[step][row] = b_ih+b_hh + W_ih@xt ----------------
__global__ __launch_bounds__(256) void k_pregates(const float* __restrict__ Wih,
                                                  const float* __restrict__ bih,
                                                  const float* __restrict__ bhh,
                                                  const float* __restrict__ seq,
                                                  float* __restrict__ pg) {
  const int b = blockIdx.x;
  const int step = b >> 2;
  const int row = (b & 3) * 256 + threadIdx.x;
  const float* sr = seq + step * 32;
  float acc = bih[row] + bhh[row];
  const float4* wr = (const float4*)(Wih + (size_t)row * 32);
  #pragma unroll
  for (int c = 0; c < 8; c++) {
    float4 w = wr[c];
    acc += w.x * sr[4*c+0] + w.y * sr[4*c+1] + w.z * sr[4*c+2] + w.w * sr[4*c+3];
  }
  pg[(size_t)step * 1024 + row] = acc;
}

// ---------------- W_hh f32 -> f16 pairs, transposed [pair j][row t] ----------------
__global__ __launch_bounds__(256) void k_w16(const float* __restrict__ Whh,
                                             unsigned int* __restrict__ w16) {
  const int p = blockIdx.x * 256 + threadIdx.x;   // 131072
  const int t = p >> 7, j = p & 127;
  float2 v = ((const float2*)Whh)[(size_t)t * 128 + j];
  __half2 h = __floats2half2_rn(v.x, v.y);
  w16[(size_t)j * 1024 + t] = *(unsigned int*)&h;
}

// ---------------- LSTM: single workgroup, 512 thr x 2 rows, W_hh f16 in VGPR+LDS ----------------
typedef _Float16 half2_t __attribute__((ext_vector_type(2)));

__device__ inline float dot2(unsigned int a, unsigned int b, float c) {
#if defined(__has_builtin) && __has_builtin(__builtin_amdgcn_fdot2)
  return __builtin_amdgcn_fdot2(__builtin_bit_cast(half2_t, a),
                                __builtin_bit_cast(half2_t, b), c, false);
#else
  __half2 ha = *(__half2*)&a, hb = *(__half2*)&b;
  float2 fa = __half22float2(ha), fb = __half22float2(hb);
  return c + fa.x * fb.x + fa.y * fb.y;
#endif
}

// P_REG = 96 pairs/row in VGPR (2 rows -> 192 regs), P_LDS = 32 pairs/row in LDS.
// LDS weight layout: [512 thr][2 rows][8 uint4 slots] with slot = c ^ (t&7) XOR swizzle
// (spreads the 64 lanes of a b128 read across all 32 banks; without it all lanes
// hit one 4-bank group = 8-way conflict).
#define LSTM_WLDS_BYTES (512*2*8*16)              // 131072
#define LSTM_GEX_OFF    LSTM_WLDS_BYTES
#define LSTM_HBUF_OFF   (LSTM_WLDS_BYTES + 4096)
#define LSTM_LDS_BYTES  (LSTM_WLDS_BYTES + 4096 + 512)

__device__ inline float fast_sig(float x) {
  return 1.f / (1.f + __expf(-x));
}
__device__ inline float fast_tanh(float x) {
  float xc = fminf(fmaxf(x, -30.f), 30.f);   // avoid inf/inf
  float e = __expf(2.f * xc);
  return (e - 1.f) / (e + 1.f);
}

// __launch_bounds__(512, 2): 2nd arg = min waves/EU -> VGPR cap 512/2 = 256.
// (round 2: a separate amdgpu_waves_per_eu attribute was ignored -> 128 cap -> spill)
__global__ void __launch_bounds__(512, 2)
k_lstm(const unsigned int* __restrict__ w16,
       const float* __restrict__ pg,
       float* __restrict__ out) {
  extern __shared__ char smem[];
  uint4* wlds = (uint4*)smem;
  float* gex = (float*)(smem + LSTM_GEX_OFF);                 // 1024 f32
  unsigned int* hbuf = (unsigned int*)(smem + LSTM_HBUF_OFF); // 128 uints = 256 f16
  const int t = threadIdx.x;          // owns rows t and t+512
  const int swz = t & 7;
  unsigned int wrA[96], wrB[96];
  #pragma unroll
  for (int j = 0; j < 96; j++) {
    wrA[j] = w16[(size_t)j * 1024 + t];
    wrB[j] = w16[(size_t)j * 1024 + t + 512];
  }
  #pragma unroll
  for (int c = 0; c < 8; c++) {
    uint4 a, b;
    a.x = w16[(size_t)(96 + 4*c + 0) * 1024 + t];
    a.y = w16[(size_t)(96 + 4*c + 1) * 1024 + t];
    a.z = w16[(size_t)(96 + 4*c + 2) * 1024 + t];
    a.w = w16[(size_t)(96 + 4*c + 3) * 1024 + t];
    b.x = w16[(size_t)(96 + 4*c + 0) * 1024 + t + 512];
    b.y = w16[(size_t)(96 + 4*c + 1) * 1024 + t + 512];
    b.z = w16[(size_t)(96 + 4*c + 2) * 1024 + t + 512];
    b.w = w16[(size_t)(96 + 4*c + 3) * 1024 + t + 512];
    wlds[(t*2 + 0) * 8 + (c ^ swz)] = a;
    wlds[(t*2 + 1) * 8 + (c ^ swz)] = b;
  }
  if (t < 128) hbuf[t] = 0u;   // h0 = 0
  float cs = 0.f;              // c_state, live in threads t<256
  __syncthreads();
  const uint4* h4 = (const uint4*)hbuf;
  float p0 = pg[t], p1 = pg[t + 512];   // software-pipelined pregate loads
  for (int step = 0; step < 256; ++step) {
    float n0 = 0.f, n1 = 0.f;
    if (step < 255) {
      n0 = pg[(size_t)(step + 1) * 1024 + t];
      n1 = pg[(size_t)(step + 1) * 1024 + t + 512];
    }
    float a0 = p0, a1 = p1;
    #pragma unroll
    for (int c = 0; c < 24; c++) {       // register-resident 96 pairs/row
      uint4 hh = h4[c];
      a0 = dot2(wrA[4*c+0], hh.x, a0);
      a0 = dot2(wrA[4*c+1], hh.y, a0);
      a0 = dot2(wrA[4*c+2], hh.z, a0);
      a0 = dot2(wrA[4*c+3], hh.w, a0);
      a1 = dot2(wrB[4*c+0], hh.x, a1);
      a1 = dot2(wrB[4*c+1], hh.y, a1);
      a1 = dot2(wrB[4*c+2], hh.z, a1);
      a1 = dot2(wrB[4*c+3], hh.w, a1);
    }
    #pragma unroll
    for (int c = 0; c < 8; c++) {        // LDS-resident 32 pairs/row
      uint4 hh = h4[24 + c];
      uint4 wa = wlds[(t*2 + 0) * 8 + (c ^ swz)];
      uint4 wb = wlds[(t*2 + 1) * 8 + (c ^ swz)];
      a0 = dot2(wa.x, hh.x, a0);
      a0 = dot2(wa.y, hh.y, a0);
      a0 = dot2(wa.z, hh.z, a0);
      a0 = dot2(wa.w, hh.w, a0);
      a1 = dot2(wb.x, hh.x, a1);
      a1 = dot2(wb.y, hh.y, a1);
      a1 = dot2(wb.z, hh.z, a1);
      a1 = dot2(wb.w, hh.w, a1);
    }
    gex[t] = a0;
    gex[t + 512] = a1;
    __syncthreads();
    if (t < 256) {
      float gi = gex[t], gf = gex[t + 256], gg = gex[t + 512], go = gex[t + 768];
      float si = fast_sig(gi);
      float sf = fast_sig(gf);
      float so = fast_sig(go);
      float tg = fast_tanh(gg);
      cs = sf * cs + si * tg;
      float hn = so * fast_tanh(cs);
      out[step * 256 + t] = hn;
      ((unsigned short*)hbuf)[t] = __half_as_ushort(__float2half(hn));
    }
    __syncthreads();
    p0 = n0;
    p1 = n1;
  }
}

extern "C" void kernel_launch(void* const* d_in, const int* in_sizes, int n_in,
                              void* d_out, int out_size, void* d_ws, size_t ws_size,
                              hipStream_t stream) {
  const float* x    = (const float*)d_in[0];
  const int*   esrc = (const int*)d_in[1];
  const int*   edst = (const int*)d_in[2];
  // d_in[3] node_graph_ids: implied by node index (n >> 12)
  const float* fc1w = (const float*)d_in[4];
  const float* fc1b = (const float*)d_in[5];
  const float* g1w  = (const float*)d_in[6];
  const float* g1b  = (const float*)d_in[7];
  const float* g2w  = (const float*)d_in[8];
  const float* g2b  = (const float*)d_in[9];
  const float* g3w  = (const float*)d_in[10];
  const float* g3b  = (const float*)d_in[11];
  const float* Wih  = (const float*)d_in[12];
  const float* Whh  = (const float*)d_in[13];
  const float* bih  = (const float*)d_in[14];
  const float* bhh  = (const float*)d_in[15];
  // d_in[16], d_in[17]: w_omega/u_omega — result discarded by reference

  float* ws = (float*)d_ws;
  int*            off  = (int*)(ws + W_OFF);
  float*          deg2 = ws + W_DEG2;
  unsigned short* srt  = (unsigned short*)(ws + W_SRT);
  float*          ha   = ws + W_HA;
  float*          hb   = ws + W_HB;
  float*          gsum = ws + W_GSUM;
  float*          seq  = ws + W_SEQ;
  float*          pg   = ws + W_PG;
  unsigned int*   w16  = (unsigned int*)(ws + W_W16);

  hipMemsetAsync(gsum, 0, 1024 * 4, stream);
  k_sort<<<256, 1024, SORT_LDS_BYTES, stream>>>(esrc, edst, off, (float2*)deg2, srt);
  k_w16<<<512, 256, 0, stream>>>(Whh, w16);
  k_conv<2, 12, true,  false><<<4096, 256, 0, stream>>>(off, srt, deg2, g1w, g1b, ha, nullptr);
  k_conv<12, 12, false, false><<<4096, 256, 0, stream>>>(off, srt, ha, g2w, g2b, hb, nullptr);
  k_conv<12, 4, false, true ><<<4096, 256, 0, stream>>>(off, srt, hb, g3w, g3b, nullptr, gsum);
  k_small<<<1, 256, 0, stream>>>(x, fc1w, fc1b, gsum, seq);
  k_pregates<<<1024, 256, 0, stream>>>(Wih, bih, bhh, seq, pg);
  k_lstm<<<1, 512, LSTM_LDS_BYTES, stream>>>(w16, pg, (float*)d_out);
}